// Round 1
// baseline (235.016 us; speedup 1.0000x reference)
//
#include <hip/hip_runtime.h>
#include <hip/hip_bf16.h>
#include <float.h>
#include <math.h>

#define T_DIM 2048
#define C_DIM 512
#define H_DIM 8
#define DH_DIM 64
#define WIN_R 48
#define NW 97           // 2*WIN+1
#define QKV_LD (3 * C_DIM)

// ---------------------------------------------------------------------------
// fp32 GEMM: C[M,N] = A[M,K] * B[K,N], row-major. M%64==0, N%64==0, K%16==0.
// 64x64 tile, BK=16, 256 threads, 4x4 accumulators per thread.
// LDS pad +4: keeps float4 (16B) alignment (stride 68*4=272 B, %16==0) and
// limits bank aliasing to 2-way (free on CDNA4).
// ---------------------------------------------------------------------------
__global__ __launch_bounds__(256) void gemm_f32(const float* __restrict__ A,
                                                const float* __restrict__ B,
                                                float* __restrict__ C,
                                                int M, int N, int K) {
  constexpr int BM = 64, BN = 64, BK = 16;
  __shared__ float As[BK][BM + 4];   // [k][m]
  __shared__ float Bs[BK][BN + 4];   // [k][n]

  const int tid = threadIdx.x;
  const int tx = tid & 15;   // n-dir thread
  const int ty = tid >> 4;   // m-dir thread
  const int m0 = blockIdx.y * BM;
  const int n0 = blockIdx.x * BN;

  // A staging: each thread loads float4; row = tid/4 (0..63), col = (tid%4)*4
  const int a_row = tid >> 2;
  const int a_col = (tid & 3) * 4;
  // B staging: row = tid/16 (0..15), col = (tid%16)*4
  const int b_row = tid >> 4;
  const int b_col = (tid & 15) * 4;

  float acc[4][4] = {};

  for (int k0 = 0; k0 < K; k0 += BK) {
    float4 av = *(const float4*)&A[(size_t)(m0 + a_row) * K + k0 + a_col];
    float4 bv = *(const float4*)&B[(size_t)(k0 + b_row) * N + n0 + b_col];
    As[a_col + 0][a_row] = av.x;
    As[a_col + 1][a_row] = av.y;
    As[a_col + 2][a_row] = av.z;
    As[a_col + 3][a_row] = av.w;
    *(float4*)&Bs[b_row][b_col] = bv;
    __syncthreads();

#pragma unroll
    for (int kk = 0; kk < BK; ++kk) {
      float4 a = *(const float4*)&As[kk][ty * 4];
      float4 b = *(const float4*)&Bs[kk][tx * 4];
      acc[0][0] += a.x * b.x; acc[0][1] += a.x * b.y; acc[0][2] += a.x * b.z; acc[0][3] += a.x * b.w;
      acc[1][0] += a.y * b.x; acc[1][1] += a.y * b.y; acc[1][2] += a.y * b.z; acc[1][3] += a.y * b.w;
      acc[2][0] += a.z * b.x; acc[2][1] += a.z * b.y; acc[2][2] += a.z * b.z; acc[2][3] += a.z * b.w;
      acc[3][0] += a.w * b.x; acc[3][1] += a.w * b.y; acc[3][2] += a.w * b.z; acc[3][3] += a.w * b.w;
    }
    __syncthreads();
  }

#pragma unroll
  for (int i = 0; i < 4; ++i) {
    float4 o = make_float4(acc[i][0], acc[i][1], acc[i][2], acc[i][3]);
    *(float4*)&C[(size_t)(m0 + ty * 4 + i) * N + n0 + tx * 4] = o;
  }
}

// ---------------------------------------------------------------------------
// Permuted sliding-window attention. One 128-thread block per (t, h).
// qkv layout: [T][3C]; Q at col h*64, K at 512+h*64, V at 1024+h*64.
// Output Y[T][C]: y_pi[t] scattered to row perm[t] (== applying inv_perm).
// ---------------------------------------------------------------------------
__global__ __launch_bounds__(128) void attn_kernel(const float* __restrict__ qkv,
                                                   const int* __restrict__ perms,
                                                   float* __restrict__ Y) {
  const int t = blockIdx.x;
  const int h = blockIdx.y;
  const int tid = threadIdx.x;

  __shared__ float q_s[DH_DIM];
  __shared__ float w_s[128];
  __shared__ float red[128];
  __shared__ int oi[NW];

  const int p = perms[h * T_DIM + t];   // original index of this permuted slot

  if (tid < DH_DIM)
    q_s[tid] = qkv[(size_t)p * QKV_LD + h * DH_DIM + tid];

  const int pi = t - WIN_R + tid;
  const int idx = min(max(pi, 0), T_DIM - 1);
  bool valid = false;
  int orig = 0;
  if (tid < NW) {
    orig = perms[h * T_DIM + idx];
    oi[tid] = orig;
    valid = (orig <= p) && (pi >= 0) && (pi < T_DIM);
  }
  __syncthreads();

  // scores
  float score = -FLT_MAX;
  if (valid) {
    const float4* kr = (const float4*)(qkv + (size_t)orig * QKV_LD + C_DIM + h * DH_DIM);
    const float4* qq = (const float4*)q_s;
    float s = 0.f;
#pragma unroll
    for (int d4 = 0; d4 < DH_DIM / 4; ++d4) {
      float4 kv = kr[d4];
      float4 qv = qq[d4];
      s += qv.x * kv.x + qv.y * kv.y + qv.z * kv.z + qv.w * kv.w;
    }
    score = s * 0.125f;  // 1/sqrt(64)
  }

  // max reduce over 128 slots (invalid = -FLT_MAX)
  red[tid] = score;
  __syncthreads();
  for (int s = 64; s > 0; s >>= 1) {
    if (tid < s) red[tid] = fmaxf(red[tid], red[tid + s]);
    __syncthreads();
  }
  const float mx = red[0];
  __syncthreads();

  // exp + sum reduce
  const float e = valid ? expf(score - mx) : 0.f;
  red[tid] = e;
  __syncthreads();
  for (int s = 64; s > 0; s >>= 1) {
    if (tid < s) red[tid] += red[tid + s];
    __syncthreads();
  }
  const float denom = red[0];
  __syncthreads();

  w_s[tid] = e / denom;
  __syncthreads();

  // PV: 64 lanes, one per dim; coalesced 256B row reads of V
  if (tid < DH_DIM) {
    float acc = 0.f;
#pragma unroll 4
    for (int j = 0; j < NW; ++j) {
      acc += w_s[j] * qkv[(size_t)oi[j] * QKV_LD + 2 * C_DIM + h * DH_DIM + tid];
    }
    Y[(size_t)p * C_DIM + h * DH_DIM + tid] = acc;
  }
}

// ---------------------------------------------------------------------------
extern "C" void kernel_launch(void* const* d_in, const int* in_sizes, int n_in,
                              void* d_out, int out_size, void* d_ws, size_t ws_size,
                              hipStream_t stream) {
  const float* x     = (const float*)d_in[0];   // [2048][512]
  const float* Wqkv  = (const float*)d_in[1];   // [512][1536]
  const float* Wout  = (const float*)d_in[2];   // [512][512]
  const int*   perms = (const int*)d_in[3];     // [8][2048]
  float* out = (float*)d_out;                   // [2048][512]

  float* qkv = (float*)d_ws;                          // [2048][1536]
  float* Y   = qkv + (size_t)T_DIM * QKV_LD;          // [2048][512]

  // qkv = x @ W_qkv
  gemm_f32<<<dim3((3 * C_DIM) / 64, T_DIM / 64), 256, 0, stream>>>(
      x, Wqkv, qkv, T_DIM, 3 * C_DIM, C_DIM);

  // attention -> Y (already un-permuted via scatter)
  attn_kernel<<<dim3(T_DIM, H_DIM), 128, 0, stream>>>(qkv, perms, Y);

  // out = Y @ W_out
  gemm_f32<<<dim3(C_DIM / 64, T_DIM / 64), 256, 0, stream>>>(
      Y, Wout, out, T_DIM, C_DIM, C_DIM);
}

// Round 2
// 145.501 us; speedup vs baseline: 1.6152x; 1.6152x over previous
//
#include <hip/hip_runtime.h>
#include <hip/hip_bf16.h>
#include <float.h>
#include <math.h>

#define T_DIM 2048
#define C_DIM 512
#define H_DIM 8
#define DH_DIM 64
#define WIN_R 48
#define NW 97
#define QKV_LD (3 * C_DIM)

typedef float f32x4 __attribute__((ext_vector_type(4)));
typedef short s16x8 __attribute__((ext_vector_type(8)));

__device__ __forceinline__ unsigned short f2bf(float f) {
  unsigned u = __float_as_uint(f);
  unsigned r = (u + 0x7fffu + ((u >> 16) & 1u)) >> 16;
  return (unsigned short)r;
}
__device__ __forceinline__ float bflo(unsigned u) { return __uint_as_float(u << 16); }
__device__ __forceinline__ float bfhi(unsigned u) { return __uint_as_float(u & 0xffff0000u); }

// async 16B global->LDS (wave-uniform base + lane*16 ordering is preserved by
// construction: lds offset == chunk*16 where chunk = i*256 + wave*64 + lane).
__device__ __forceinline__ void load16_to_lds(const void* g, void* l) {
  __builtin_amdgcn_global_load_lds(
      (const __attribute__((address_space(1))) unsigned int*)g,
      (__attribute__((address_space(3))) unsigned int*)(unsigned int)(unsigned long long)l,
      16, 0, 0);
}

// ---------------------------------------------------------------------------
// cast fp32 -> bf16, vectorized
// ---------------------------------------------------------------------------
__global__ __launch_bounds__(256) void cast_bf16(const float* __restrict__ s,
                                                 unsigned short* __restrict__ d, int n4) {
  int i = blockIdx.x * 256 + threadIdx.x;
  if (i < n4) {
    float4 v = ((const float4*)s)[i];
    ushort4 o;
    o.x = f2bf(v.x); o.y = f2bf(v.y); o.z = f2bf(v.z); o.w = f2bf(v.w);
    ((ushort4*)d)[i] = o;
  }
}

// ---------------------------------------------------------------------------
// transpose + cast: dst[c*R + r] = bf16(src[r*C + c]).  32x32 tiles.
// ---------------------------------------------------------------------------
__global__ __launch_bounds__(256) void transpose_cast(const float* __restrict__ src,
                                                      unsigned short* __restrict__ dst,
                                                      int R, int Cc) {
  __shared__ float tile[32][33];
  const int bx = blockIdx.x * 32;  // col tile in src
  const int by = blockIdx.y * 32;  // row tile in src
  const int tx = threadIdx.x & 31;
  const int ty = threadIdx.x >> 5;  // 0..7
#pragma unroll
  for (int i = 0; i < 4; ++i) {
    int r = ty + i * 8;
    tile[r][tx] = src[(size_t)(by + r) * Cc + bx + tx];
  }
  __syncthreads();
#pragma unroll
  for (int i = 0; i < 4; ++i) {
    int r = ty + i * 8;
    dst[(size_t)(bx + r) * R + by + tx] = f2bf(tile[tx][r]);
  }
}

// ---------------------------------------------------------------------------
// bf16 MFMA GEMM: C[M,N] = A[M,K] * BT[N,K]^T.  256 threads = 4 waves (2x2),
// wave tile (BM/2)x(BN/2) in 16x16x32 MFMA units. global_load_lds staging.
// ---------------------------------------------------------------------------
template <int BM, int BN, typename OutT>
__global__ __launch_bounds__(256) void gemm_bf16(const unsigned short* __restrict__ A,
                                                 const unsigned short* __restrict__ BT,
                                                 OutT* __restrict__ C,
                                                 int M, int N, int K) {
  constexpr int BK = 32;
  constexpr int BM2 = BM / 2, BN2 = BN / 2;
  constexpr int MT = BM2 / 16, NT = BN2 / 16;
  constexpr int IA = (BM * 4) / 256;  // 16B chunks per thread for A tile
  constexpr int IB = (BN * 4) / 256;

  __shared__ unsigned short lA[BM * BK];
  __shared__ unsigned short lB[BN * BK];

  const int tid = threadIdx.x;
  const int lane = tid & 63;
  const int w = tid >> 6;
  const int wr = w >> 1, wc = w & 1;
  const int m0 = blockIdx.y * BM;
  const int n0 = blockIdx.x * BN;

  const int fm = lane & 15;
  const int q8 = (lane >> 4) * 8;

  f32x4 acc[MT][NT] = {};

  for (int k0 = 0; k0 < K; k0 += BK) {
    __syncthreads();
#pragma unroll
    for (int i = 0; i < IA; ++i) {
      int chunk = i * 256 + tid;
      int row = chunk >> 2;
      int c8 = (chunk & 3) * 8;
      load16_to_lds(&A[(size_t)(m0 + row) * K + k0 + c8], &lA[chunk * 8]);
    }
#pragma unroll
    for (int i = 0; i < IB; ++i) {
      int chunk = i * 256 + tid;
      int row = chunk >> 2;
      int c8 = (chunk & 3) * 8;
      load16_to_lds(&BT[(size_t)(n0 + row) * K + k0 + c8], &lB[chunk * 8]);
    }
    __syncthreads();

    s16x8 a[MT], b[NT];
#pragma unroll
    for (int mi = 0; mi < MT; ++mi)
      a[mi] = *(const s16x8*)&lA[(wr * BM2 + mi * 16 + fm) * BK + q8];
#pragma unroll
    for (int ni = 0; ni < NT; ++ni)
      b[ni] = *(const s16x8*)&lB[(wc * BN2 + ni * 16 + fm) * BK + q8];
#pragma unroll
    for (int mi = 0; mi < MT; ++mi)
#pragma unroll
      for (int ni = 0; ni < NT; ++ni)
        acc[mi][ni] = __builtin_amdgcn_mfma_f32_16x16x32_bf16(a[mi], b[ni], acc[mi][ni], 0, 0, 0);
  }

  // epilogue: D row = quad*4+reg, col = lane&15
#pragma unroll
  for (int mi = 0; mi < MT; ++mi) {
#pragma unroll
    for (int ni = 0; ni < NT; ++ni) {
#pragma unroll
      for (int r = 0; r < 4; ++r) {
        int row = m0 + wr * BM2 + mi * 16 + (lane >> 4) * 4 + r;
        int col = n0 + wc * BN2 + ni * 16 + fm;
        float v = acc[mi][ni][r];
        if constexpr (sizeof(OutT) == 2)
          C[(size_t)row * N + col] = (OutT)f2bf(v);
        else
          C[(size_t)row * N + col] = (OutT)v;
      }
    }
  }
}

// ---------------------------------------------------------------------------
// Attention: one wave per (t,h). 4 waves / 256-thread block.
// qkv is bf16 [T][3C]; output Y bf16 [T][C] scattered via perm (== inv_perm).
// ---------------------------------------------------------------------------
__global__ __launch_bounds__(256) void attn_wave(const unsigned short* __restrict__ qkv,
                                                 const int* __restrict__ perms,
                                                 unsigned short* __restrict__ Y) {
  __shared__ float q_s[4][64];
  __shared__ float w_s[4][104];
  __shared__ int oi[4][104];

  const int tid = threadIdx.x;
  const int lane = tid & 63;
  const int w = tid >> 6;
  const int g = blockIdx.x * 4 + w;
  const int h = g >> 11;           // g / T
  const int t = g & (T_DIM - 1);   // g % T

  const int p = perms[h * T_DIM + t];

  // q into LDS (fp32)
  q_s[w][lane] = bflo((unsigned)qkv[(size_t)p * QKV_LD + h * DH_DIM + lane] << 16 >> 16 |
                      ((unsigned)qkv[(size_t)p * QKV_LD + h * DH_DIM + lane] << 16));
  // (simpler: direct) -- overwrite with clean version:
  q_s[w][lane] = bflo((unsigned)qkv[(size_t)p * QKV_LD + h * DH_DIM + lane]);

  // neighbor slots: s0 = lane, s1 = lane + 64
  const int pi0 = t - WIN_R + lane;
  const int pi1 = pi0 + 64;
  const int idx0 = min(max(pi0, 0), T_DIM - 1);
  const int idx1 = min(max(pi1, 0), T_DIM - 1);
  const int orig0 = perms[h * T_DIM + idx0];
  const int orig1 = perms[h * T_DIM + idx1];
  const bool valid0 = (orig0 <= p) && (pi0 >= 0) && (pi0 < T_DIM);
  const bool valid1 = (lane < 33) && (orig1 <= p) && (pi1 >= 0) && (pi1 < T_DIM);

  oi[w][lane] = orig0;
  if (lane < 36) oi[w][lane + 64] = (lane < 33) ? orig1 : 0;
  __syncthreads();

  // scores (both slots; bf16 K rows, fp32 math)
  const uint4* k0p = (const uint4*)(qkv + (size_t)orig0 * QKV_LD + C_DIM + h * DH_DIM);
  const uint4* k1p = (const uint4*)(qkv + (size_t)orig1 * QKV_LD + C_DIM + h * DH_DIM);
  const float4* qq = (const float4*)q_s[w];
  float s0 = 0.f, s1 = 0.f;
#pragma unroll
  for (int i = 0; i < 8; ++i) {
    uint4 k0v = k0p[i];
    uint4 k1v = k1p[i];
    float4 qa = qq[2 * i], qb = qq[2 * i + 1];
    s0 += bflo(k0v.x) * qa.x + bfhi(k0v.x) * qa.y + bflo(k0v.y) * qa.z + bfhi(k0v.y) * qa.w +
          bflo(k0v.z) * qb.x + bfhi(k0v.z) * qb.y + bflo(k0v.w) * qb.z + bfhi(k0v.w) * qb.w;
    s1 += bflo(k1v.x) * qa.x + bfhi(k1v.x) * qa.y + bflo(k1v.y) * qa.z + bfhi(k1v.y) * qa.w +
          bflo(k1v.z) * qb.x + bfhi(k1v.z) * qb.y + bflo(k1v.w) * qb.z + bfhi(k1v.w) * qb.w;
  }
  s0 *= 0.125f;
  s1 *= 0.125f;

  // wave softmax
  float m = fmaxf(valid0 ? s0 : -FLT_MAX, valid1 ? s1 : -FLT_MAX);
#pragma unroll
  for (int off = 32; off > 0; off >>= 1) m = fmaxf(m, __shfl_xor(m, off, 64));
  const float e0 = valid0 ? __expf(s0 - m) : 0.f;
  const float e1 = valid1 ? __expf(s1 - m) : 0.f;
  float sum = e0 + e1;
#pragma unroll
  for (int off = 32; off > 0; off >>= 1) sum += __shfl_xor(sum, off, 64);
  const float inv = 1.f / sum;

  w_s[w][lane] = e0 * inv;
  if (lane < 36) w_s[w][lane + 64] = (lane < 33) ? e1 * inv : 0.f;
  __syncthreads();

  // PV: lane = (jg, dq); dq covers dims dq*4..dq*4+3, jg strides neighbors by 4
  const int dq = lane & 15;
  const int jg = lane >> 4;
  float4 acc = make_float4(0.f, 0.f, 0.f, 0.f);
  for (int j = jg; j < 100; j += 4) {
    const float wj = w_s[w][j];
    const int orig = oi[w][j];
    uint2 vv = *(const uint2*)(qkv + (size_t)orig * QKV_LD + 2 * C_DIM + h * DH_DIM + dq * 4);
    acc.x += wj * bflo(vv.x);
    acc.y += wj * bfhi(vv.x);
    acc.z += wj * bflo(vv.y);
    acc.w += wj * bfhi(vv.y);
  }
  // reduce over the 4 jg groups (lanes dq, dq+16, dq+32, dq+48)
#pragma unroll
  for (int off = 16; off <= 32; off <<= 1) {
    acc.x += __shfl_xor(acc.x, off, 64);
    acc.y += __shfl_xor(acc.y, off, 64);
    acc.z += __shfl_xor(acc.z, off, 64);
    acc.w += __shfl_xor(acc.w, off, 64);
  }
  if (jg == 0) {
    ushort4 o;
    o.x = f2bf(acc.x); o.y = f2bf(acc.y); o.z = f2bf(acc.z); o.w = f2bf(acc.w);
    *(ushort4*)&Y[(size_t)p * C_DIM + h * DH_DIM + dq * 4] = o;
  }
}

// ---------------------------------------------------------------------------
extern "C" void kernel_launch(void* const* d_in, const int* in_sizes, int n_in,
                              void* d_out, int out_size, void* d_ws, size_t ws_size,
                              hipStream_t stream) {
  const float* x     = (const float*)d_in[0];   // [2048][512]
  const float* Wqkv  = (const float*)d_in[1];   // [512][1536]
  const float* Wout  = (const float*)d_in[2];   // [512][512]
  const int*   perms = (const int*)d_in[3];     // [8][2048]
  float* out = (float*)d_out;                   // [2048][512]

  unsigned short* xbf   = (unsigned short*)d_ws;                    // 2048*512
  unsigned short* WqkvT = xbf + (size_t)T_DIM * C_DIM;              // 1536*512 (transposed)
  unsigned short* WoutT = WqkvT + (size_t)QKV_LD * C_DIM;           // 512*512 (transposed)
  unsigned short* qkvbf = WoutT + (size_t)C_DIM * C_DIM;            // 2048*1536
  unsigned short* Ybf   = qkvbf + (size_t)T_DIM * QKV_LD;           // 2048*512

  cast_bf16<<<(T_DIM * C_DIM / 4 + 255) / 256, 256, 0, stream>>>(x, xbf, T_DIM * C_DIM / 4);
  transpose_cast<<<dim3(QKV_LD / 32, C_DIM / 32), 256, 0, stream>>>(Wqkv, WqkvT, C_DIM, QKV_LD);
  transpose_cast<<<dim3(C_DIM / 32, C_DIM / 32), 256, 0, stream>>>(Wout, WoutT, C_DIM, C_DIM);

  // qkv = x @ Wqkv  (bf16 out)
  gemm_bf16<128, 128, unsigned short><<<dim3(QKV_LD / 128, T_DIM / 128), 256, 0, stream>>>(
      xbf, WqkvT, qkvbf, T_DIM, QKV_LD, C_DIM);

  attn_wave<<<T_DIM * H_DIM / 4, 256, 0, stream>>>(qkvbf, perms, Ybf);

  // out = Y @ Wout  (fp32 out)
  gemm_bf16<64, 64, float><<<dim3(C_DIM / 64, T_DIM / 64), 256, 0, stream>>>(
      Ybf, WoutT, out, T_DIM, C_DIM, C_DIM);
}